// Round 6
// baseline (363.677 us; speedup 1.0000x reference)
//
#include <hip/hip_runtime.h>
#include <cstdint>
#include <cstddef>

#define N_B 128
#define N_I 784
#define N_H 410
#define N_O 10
#define TT  300
#define KL  64
#define NW  26          // bitmask words per (n,t) (832 bits, K-padded)
#define NKS 13          // layer-1 K-steps of 64 (832)
#define NTILES 26       // layer-1 N-tiles of 16 (410 -> 416)
#define SSTR 448        // s1 row stride (7*64, layer-2 K-padded)
#define NKS2 7          // layer-2 K-steps of 64 (448)
#define NDIG 4          // base-256 digits of round(W * 2^28)

typedef int v4i __attribute__((ext_vector_type(4)));

__device__ __forceinline__ uint32_t expand4(uint32_t v) {
  return (v * 0x00204081u) & 0x01010101u;   // 4 bits -> 4 bytes (0/1)
}

// ---- k_pack: thread owns (n,t), all 26 words; 32-unrolled loads for ILP ----
__global__ void k_pack(const float* __restrict__ rand_u, const float* __restrict__ img,
                       uint32_t* __restrict__ s0w) {
  int n = blockIdx.y;
  int t = blockIdx.x * 64 + threadIdx.x;
  if (t >= TT) return;
  const float* rb = rand_u + (size_t)n * N_I * TT + t;
  const float* ib = img + (size_t)n * N_I;
  uint32_t* dst = s0w + ((size_t)n * TT + t) * NW;
  #pragma unroll 1
  for (int w = 0; w < 25; ++w) {
    int ib32 = w * 32;
    float r[32];
    #pragma unroll
    for (int b = 0; b < 32; ++b) {
      int i = ib32 + b;
      r[b] = (i < N_I) ? rb[(size_t)i * TT] : 2.0f;   // 2.0 > any p -> no spike
    }
    uint32_t bits = 0;
    #pragma unroll
    for (int b = 0; b < 32; ++b) {
      int i = ib32 + b;
      float p = (i < N_I) ? ib[i] : 0.0f;             // uniform -> scalar load
      bits |= (r[b] < p ? 1u : 0u) << b;
    }
    dst[w] = bits;
  }
  dst[25] = 0;
}

// ---- k_eps: raw eps [0..63]; 2^-28-scaled eps [64..127] ----
__global__ void k_eps(double* __restrict__ epsb) {
  int k = threadIdx.x;
  if (k < KL) {
    double td = (double)k;
    double e = (td / 10.0) * exp(1.0 - td / 10.0);
    epsb[k] = e;
    epsb[KL + k] = e * (1.0 / 268435456.0);
  }
}

// ---- k_bprep: W1 -> 4 signed-i8 digit matrices, MFMA fragment-major ----
__global__ void k_bprep(const float* __restrict__ W1, v4i* __restrict__ Bf) {
  int bid  = blockIdx.x;              // ((d*NTILES + nt)*NKS + ks)
  int lane = threadIdx.x;
  int ks   = bid % NKS;
  int rest = bid / NKS;
  int nt   = rest % NTILES;
  int d    = rest / NTILES;
  int o     = nt * 16 + (lane & 15);
  int kbase = ks * 64 + (lane >> 4) * 16;
  uint32_t wds[4] = {0, 0, 0, 0};
  for (int j = 0; j < 16; ++j) {
    int k = kbase + j;
    int dig = 0;
    if (o < N_H && k < N_I) {
      double w = (double)W1[(size_t)o * N_I + k];
      int r = (int)llround(w * 268435456.0);
      for (int dd = 0; dd <= d; ++dd) {
        dig = (int)(int8_t)(uint8_t)(r & 255);
        r = (r - dig) >> 8;
      }
    }
    wds[j >> 2] |= ((uint32_t)(uint8_t)(int8_t)dig) << (8 * (j & 3));
  }
  v4i v; v[0] = (int)wds[0]; v[1] = (int)wds[1]; v[2] = (int)wds[2]; v[3] = (int)wds[3];
  Bf[(size_t)bid * 64 + lane] = v;
}

// ---- k_bprep2: W2 -> 4 signed-i8 digit matrices, fragment-major ----
__global__ void k_bprep2(const float* __restrict__ W2, v4i* __restrict__ Bf2) {
  int bid  = blockIdx.x;              // d*NKS2 + ks
  int lane = threadIdx.x;
  int ks = bid % NKS2, d = bid / NKS2;
  int o     = lane & 15;
  int kbase = ks * 64 + (lane >> 4) * 16;
  uint32_t wds[4] = {0, 0, 0, 0};
  for (int j = 0; j < 16; ++j) {
    int k = kbase + j;
    int dig = 0;
    if (o < N_O && k < N_H) {
      double w = (double)W2[(size_t)o * N_H + k];
      int r = (int)llround(w * 268435456.0);
      for (int dd = 0; dd <= d; ++dd) {
        dig = (int)(int8_t)(uint8_t)(r & 255);
        r = (r - dig) >> 8;
      }
    }
    wds[j >> 2] |= ((uint32_t)(uint8_t)(int8_t)dig) << (8 * (j & 3));
  }
  v4i v; v[0] = (int)wds[0]; v[1] = (int)wds[1]; v[2] = (int)wds[2]; v[3] = (int)wds[3];
  Bf2[(size_t)bid * 64 + lane] = v;
}

// ---- k_fused: gemm1 (i8-digit MFMA) + truncated-IIR SRM FIR + threshold -> s1 ----
// Single wave per block; grid (26 nt, 128 n). Five 64-t chunks, t-serial scan.
// A expanded bitmask->bytes in registers; B prefetch-double-buffered from L2;
// a1 handoff via 2-buffer LDS tile (prev tile == x[t-64] ring). No barriers.
__global__ __launch_bounds__(64) void k_fused(const uint32_t* __restrict__ s0w,
                                              const v4i* __restrict__ Bf,
                                              uint8_t* __restrict__ s1) {
  __shared__ double tile[2][64][17];                       // 17408 B, padded rows
  __shared__ __attribute__((aligned(16))) uint8_t btile[64][16];
  int lane = threadIdx.x;
  int nt = blockIdx.x, n = blockIdx.y;
  int lrow = lane & 15, quad = lane >> 4;
  int wsel = quad >> 1, hsel = (quad & 1) * 16;
  const double q   = exp(-0.1);
  const double q64 = exp(-6.4);
  const double cS  = (exp(1.0) / 10.0) * (1.0 / 268435456.0);
  double s1a = 0.0, s2a = 0.0, s1b = 0.0, s2b = 0.0;
  const v4i* bb = Bf + (size_t)nt * NKS * 64 + lane;
  const size_t dstr = (size_t)NTILES * NKS * 64;
  const uint32_t* srow = s0w + (size_t)n * TT * NW;
  uint8_t* sbase = s1 + (size_t)n * TT * SSTR + nt * 16;

  for (int ch = 0; ch < 5; ++ch) {
    int t0 = ch * 64;
    v4i acc[4][NDIG];
    #pragma unroll
    for (int mt = 0; mt < 4; ++mt)
      #pragma unroll
      for (int d = 0; d < NDIG; ++d) { acc[mt][d][0]=0; acc[mt][d][1]=0; acc[mt][d][2]=0; acc[mt][d][3]=0; }

    // K-loop with 1-deep prefetch of B fragments and A bitmask dwords
    v4i bcur[NDIG]; uint32_t acur[4];
    #pragma unroll
    for (int d = 0; d < NDIG; ++d) bcur[d] = bb[(size_t)d * dstr];
    #pragma unroll
    for (int mt = 0; mt < 4; ++mt) {
      int row = t0 + mt * 16 + lrow; if (row > TT - 1) row = TT - 1;  // clamp (values unused)
      acur[mt] = srow[(size_t)row * NW + wsel];
    }
    for (int ks = 0; ks < NKS; ++ks) {
      int ks2 = (ks + 1 < NKS) ? ks + 1 : ks;
      v4i bnxt[NDIG]; uint32_t anxt[4];
      #pragma unroll
      for (int d = 0; d < NDIG; ++d) bnxt[d] = bb[(size_t)d * dstr + ks2 * 64];
      #pragma unroll
      for (int mt = 0; mt < 4; ++mt) {
        int row = t0 + mt * 16 + lrow; if (row > TT - 1) row = TT - 1;
        anxt[mt] = srow[(size_t)row * NW + ks2 * 2 + wsel];
      }
      #pragma unroll
      for (int mt = 0; mt < 4; ++mt) {
        uint32_t h = (acur[mt] >> hsel) & 0xFFFFu;
        v4i af;
        af[0] = (int)expand4(h & 0xF);
        af[1] = (int)expand4((h >> 4) & 0xF);
        af[2] = (int)expand4((h >> 8) & 0xF);
        af[3] = (int)expand4((h >> 12) & 0xF);
        #pragma unroll
        for (int d = 0; d < NDIG; ++d)
          acc[mt][d] = __builtin_amdgcn_mfma_i32_16x16x64_i8(af, bcur[d], acc[mt][d], 0, 0, 0);
      }
      #pragma unroll
      for (int d = 0; d < NDIG; ++d) bcur[d] = bnxt[d];
      #pragma unroll
      for (int mt = 0; mt < 4; ++mt) acur[mt] = anxt[mt];
    }

    // digit combine (exact integer < 2^53) + transpose to LDS tile
    int tb = ch & 1;
    #pragma unroll
    for (int mt = 0; mt < 4; ++mt)
      #pragma unroll
      for (int r = 0; r < 4; ++r) {
        double v = (double)acc[mt][0][r]
                 + 256.0      * (double)acc[mt][1][r]
                 + 65536.0    * (double)acc[mt][2][r]
                 + 16777216.0 * (double)acc[mt][3][r];
        tile[tb][mt * 16 + quad * 4 + r][lrow] = v;      // row = t-t0, col = o (C/D verified)
      }

    // t-serial scan (verified fir1i recurrence), lanes 0..15 (o = lane)
    int jmax = TT - t0; if (jmax > 64) jmax = 64;
    if (lane < 16) {
      if (ch == 0) {
        for (int j = 0; j < jmax; ++j) {                 // t < 64: no tail yet
          double xa = tile[0][j][lane];
          s2a = q * (s2a + s1a);
          s1a = q * s1a + xa;
          btile[j][lane] = (cS * s2a >= 10.0) ? 1 : 0;
        }
      } else {
        for (int j = 0; j < jmax; ++j) {
          double xb = tile[tb ^ 1][j][lane];             // x[t-64] = prev chunk, same j
          double xa = tile[tb][j][lane];
          s2b = q * (s2b + s1b);
          s1b = q * s1b + xb;
          s2a = q * (s2a + s1a);
          s1a = q * s1a + xa;
          double y = cS * (s2a - q64 * (s2b + 64.0 * s1b));
          btile[j][lane] = (y >= 10.0) ? 1 : 0;
        }
      }
    }

    // write-out: lane = t offset, one 16B row per t
    if (lane < jmax) {
      uint4 v = *(const uint4*)&btile[lane][0];
      *(uint4*)(sbase + (size_t)(t0 + lane) * SSTR) = v;
    }
  }
}

// ---- k_gemm2m: layer-2 exact int8-digit MFMA; a2 integer-valued f64 (x 2^28) ----
__global__ void k_gemm2m(const uint8_t* __restrict__ s1, const v4i* __restrict__ Bf2,
                         double* __restrict__ a2) {
  int tid = threadIdx.x;
  int wave = tid >> 6, lane = tid & 63;
  int m0 = (blockIdx.x * 4 + wave) * 16;
  int lrow = lane & 15, quad = lane >> 4;
  v4i acc[NDIG];
  #pragma unroll
  for (int d = 0; d < NDIG; ++d) { acc[d][0]=0; acc[d][1]=0; acc[d][2]=0; acc[d][3]=0; }
  const uint8_t* arow = s1 + (size_t)(m0 + lrow) * SSTR + quad * 16;
  for (int ks = 0; ks < NKS2; ++ks) {
    v4i af = *(const v4i*)(arow + ks * 64);
    #pragma unroll
    for (int d = 0; d < NDIG; ++d) {
      v4i bf = Bf2[(size_t)(d * NKS2 + ks) * 64 + lane];
      acc[d] = __builtin_amdgcn_mfma_i32_16x16x64_i8(af, bf, acc[d], 0, 0, 0);
    }
  }
  int o = lrow;
  if (o < N_O) {
    #pragma unroll
    for (int r = 0; r < 4; ++r) {
      int m = m0 + quad * 4 + r;
      int nn = m / TT;
      int t = m - nn * TT;
      double v = (double)acc[0][r]
               + 256.0      * (double)acc[1][r]
               + 65536.0    * (double)acc[2][r]
               + 16777216.0 * (double)acc[3][r];
      a2[((size_t)nn * N_O + o) * TT + t] = v;
    }
  }
}

// ---- k_fir2: f64 FIR (scaled eps) + threshold -> final spikes ----
__global__ void k_fir2(const double* __restrict__ a2, const double* __restrict__ epsb,
                       float* __restrict__ out) {
  int flat = blockIdx.x * 256 + threadIdx.x;
  if (flat >= N_B * N_O * TT) return;
  int t    = flat % TT;
  int rest = flat / TT;
  int o    = rest % N_O;
  int nn   = rest / N_O;
  const double* arow = a2 + ((size_t)nn * N_O + o) * TT;
  const double* epsS = epsb + KL;     // scaled eps[k] at 64+k
  double u = 0.0;
  int kmax = (t < KL - 1) ? t : (KL - 1);
  for (int k = 0; k <= kmax; ++k) u += epsS[k] * arow[t - k];
  out[((size_t)nn * N_O + o) * TT + t] = (u >= 10.0) ? 1.0f : 0.0f;
}

extern "C" void kernel_launch(void* const* d_in, const int* in_sizes, int n_in,
                              void* d_out, int out_size, void* d_ws, size_t ws_size,
                              hipStream_t stream) {
  const float* img   = (const float*)d_in[0];
  const float* randu = (const float*)d_in[1];
  const float* W1    = (const float*)d_in[2];
  const float* W2    = (const float*)d_in[3];
  float* out = (float*)d_out;

  char* ws = (char*)d_ws;
  size_t off = 0;
  auto alloc = [&](size_t bytes) -> void* {
    void* p = ws + off;
    off = (off + bytes + 511) & ~(size_t)511;
    return p;
  };
  uint32_t* s0w  = (uint32_t*)alloc((size_t)N_B * TT * NW * sizeof(uint32_t));   // 4.0 MB
  v4i*      Bf   = (v4i*)     alloc((size_t)NDIG * NTILES * NKS * 64 * 16);      // 1.4 MB
  v4i*      Bf2  = (v4i*)     alloc((size_t)NDIG * NKS2 * 64 * 16);
  double*   epsb = (double*)  alloc(128 * sizeof(double));
  uint8_t*  s1   = (uint8_t*) alloc((size_t)N_B * TT * SSTR);                    // 17.2 MB
  double*   a2   = (double*)  alloc((size_t)N_B * N_O * TT * sizeof(double));    // 3.1 MB
  if (off > ws_size) return;

  k_pack  <<<dim3(5, N_B), 64, 0, stream>>>(randu, img, s0w);
  k_eps   <<<dim3(1), 64, 0, stream>>>(epsb);
  k_bprep <<<dim3(NDIG * NTILES * NKS), 64, 0, stream>>>(W1, Bf);
  k_bprep2<<<dim3(NDIG * NKS2), 64, 0, stream>>>(W2, Bf2);

  k_fused <<<dim3(NTILES, N_B), 64, 0, stream>>>(s0w, Bf, s1);
  k_gemm2m<<<dim3(N_B * TT / 64), 256, 0, stream>>>(s1, Bf2, a2);
  k_fir2  <<<dim3((N_B * N_O * TT + 255) / 256), 256, 0, stream>>>(a2, epsb, out);
}

// Round 7
// 356.159 us; speedup vs baseline: 1.0211x; 1.0211x over previous
//
#include <hip/hip_runtime.h>
#include <cstdint>
#include <cstddef>

#define N_B 128
#define N_I 784
#define N_H 410
#define N_O 10
#define TT  300
#define KL  64
#define NW  26          // bitmask words per (n,t) (832 bits, K-padded)
#define NKS 13          // layer-1 K-steps of 64 (832)
#define NTILES 26       // layer-1 N-tiles of 16 (410 -> 416)
#define NDIG 4          // base-256 digits of round(W * 2^28)
#define NKS2 7          // layer-2 K-steps of 64 (448)
#define S1_TILE 4800    // 300 t * 16 B per (n, nt) tile
#define S1_NSTRIDE 134400  // 28 tiles * 4800 (2 pad tiles: safe reads, zero-weighted)

typedef int v4i __attribute__((ext_vector_type(4)));

__device__ __forceinline__ uint32_t expand4(uint32_t v) {
  return (v * 0x00204081u) & 0x01010101u;   // 4 bits -> 4 bytes (0/1)
}

// ---- k_pack: thread owns (n,t), all 26 words; 32-unrolled loads for ILP ----
__global__ void k_pack(const float* __restrict__ rand_u, const float* __restrict__ img,
                       uint32_t* __restrict__ s0w) {
  int n = blockIdx.y;
  int t = blockIdx.x * 64 + threadIdx.x;
  if (t >= TT) return;
  const float* rb = rand_u + (size_t)n * N_I * TT + t;
  const float* ib = img + (size_t)n * N_I;
  uint32_t* dst = s0w + ((size_t)n * TT + t) * NW;
  #pragma unroll 1
  for (int w = 0; w < 25; ++w) {
    int ib32 = w * 32;
    float r[32];
    #pragma unroll
    for (int b = 0; b < 32; ++b) {
      int i = ib32 + b;
      r[b] = (i < N_I) ? rb[(size_t)i * TT] : 2.0f;   // 2.0 > any p -> no spike
    }
    uint32_t bits = 0;
    #pragma unroll
    for (int b = 0; b < 32; ++b) {
      int i = ib32 + b;
      float p = (i < N_I) ? ib[i] : 0.0f;             // uniform -> scalar load
      bits |= (r[b] < p ? 1u : 0u) << b;
    }
    dst[w] = bits;
  }
  dst[25] = 0;
}

// ---- k_bprepall: W1 and W2 -> signed-i8 digit matrices, MFMA fragment-major ----
__global__ void k_bprepall(const float* __restrict__ W1, const float* __restrict__ W2,
                           v4i* __restrict__ Bf, v4i* __restrict__ Bf2) {
  int bid  = blockIdx.x;
  int lane = threadIdx.x;
  if (bid < NDIG * NTILES * NKS) {                    // ---- W1 part ----
    int ks   = bid % NKS;
    int rest = bid / NKS;
    int nt   = rest % NTILES;
    int d    = rest / NTILES;
    int o     = nt * 16 + (lane & 15);
    int kbase = ks * 64 + (lane >> 4) * 16;
    uint32_t wds[4] = {0, 0, 0, 0};
    for (int j = 0; j < 16; ++j) {
      int k = kbase + j;
      int dig = 0;
      if (o < N_H && k < N_I) {
        double w = (double)W1[(size_t)o * N_I + k];
        int r = (int)llround(w * 268435456.0);
        for (int dd = 0; dd <= d; ++dd) {
          dig = (int)(int8_t)(uint8_t)(r & 255);
          r = (r - dig) >> 8;
        }
      }
      wds[j >> 2] |= ((uint32_t)(uint8_t)(int8_t)dig) << (8 * (j & 3));
    }
    v4i v; v[0] = (int)wds[0]; v[1] = (int)wds[1]; v[2] = (int)wds[2]; v[3] = (int)wds[3];
    Bf[(size_t)bid * 64 + lane] = v;
  } else {                                            // ---- W2 part ----
    int b2 = bid - NDIG * NTILES * NKS;               // d*NKS2 + ks
    int ks = b2 % NKS2, d = b2 / NKS2;
    int o     = lane & 15;
    int kbase = ks * 64 + (lane >> 4) * 16;
    uint32_t wds[4] = {0, 0, 0, 0};
    for (int j = 0; j < 16; ++j) {
      int k = kbase + j;
      int dig = 0;
      if (o < N_O && k < N_H) {
        double w = (double)W2[(size_t)o * N_H + k];
        int r = (int)llround(w * 268435456.0);
        for (int dd = 0; dd <= d; ++dd) {
          dig = (int)(int8_t)(uint8_t)(r & 255);
          r = (r - dig) >> 8;
        }
      }
      wds[j >> 2] |= ((uint32_t)(uint8_t)(int8_t)dig) << (8 * (j & 3));
    }
    v4i v; v[0] = (int)wds[0]; v[1] = (int)wds[1]; v[2] = (int)wds[2]; v[3] = (int)wds[3];
    Bf2[(size_t)b2 * 64 + lane] = v;
  }
}

// ---- k_fused2: layer-1 i8-digit MFMA + truncated-IIR SRM FIR + threshold -> s1 ----
// Block = 4 waves; grid (26 nt, 128 n). MFMA phase: wave w computes t-rows
// [w*80, w*80+80) (5 m-tiles) into LDS tile. One barrier. Scan phase: wave g
// runs t-segment [g*75, g*75+75) of the verified IIR scan; the LDS tile is the
// full x history (warm-up and x[t-64] both read from it). s1 is nt-major.
__global__ __launch_bounds__(256) void k_fused2(const uint32_t* __restrict__ s0w,
                                                const v4i* __restrict__ Bf,
                                                uint8_t* __restrict__ s1) {
  __shared__ double tile[TT][17];                    // 40800 B, padded stride
  int tid = threadIdx.x;
  int wave = tid >> 6, lane = tid & 63;
  int nt = blockIdx.x, n = blockIdx.y;
  int lrow = lane & 15, quad = lane >> 4;
  int wsel = quad >> 1, hsel = (quad & 1) * 16;
  const v4i* bb = Bf + (size_t)nt * NKS * 64 + lane;
  const size_t dstr = (size_t)NTILES * NKS * 64;
  const uint32_t* srow = s0w + (size_t)n * TT * NW;

  // ---------- MFMA phase ----------
  v4i acc[5][NDIG];
  #pragma unroll
  for (int mti = 0; mti < 5; ++mti)
    #pragma unroll
    for (int d = 0; d < NDIG; ++d) { acc[mti][d][0]=0; acc[mti][d][1]=0; acc[mti][d][2]=0; acc[mti][d][3]=0; }
  int rowc[5];
  #pragma unroll
  for (int mti = 0; mti < 5; ++mti) {
    int rr = wave * 80 + mti * 16 + lrow;
    rowc[mti] = (rr > TT - 1) ? TT - 1 : rr;         // clamp; clamped rows unused
  }
  v4i bcur[NDIG]; uint32_t acur[5];
  #pragma unroll
  for (int d = 0; d < NDIG; ++d) bcur[d] = bb[(size_t)d * dstr];
  #pragma unroll
  for (int mti = 0; mti < 5; ++mti) acur[mti] = srow[(size_t)rowc[mti] * NW + wsel];
  for (int ks = 0; ks < NKS; ++ks) {
    int ks2 = (ks + 1 < NKS) ? ks + 1 : ks;
    v4i bnxt[NDIG]; uint32_t anxt[5];
    #pragma unroll
    for (int d = 0; d < NDIG; ++d) bnxt[d] = bb[(size_t)d * dstr + ks2 * 64];
    #pragma unroll
    for (int mti = 0; mti < 5; ++mti) anxt[mti] = srow[(size_t)rowc[mti] * NW + ks2 * 2 + wsel];
    #pragma unroll
    for (int mti = 0; mti < 5; ++mti) {
      uint32_t h = (acur[mti] >> hsel) & 0xFFFFu;
      v4i af;
      af[0] = (int)expand4(h & 0xF);
      af[1] = (int)expand4((h >> 4) & 0xF);
      af[2] = (int)expand4((h >> 8) & 0xF);
      af[3] = (int)expand4((h >> 12) & 0xF);
      #pragma unroll
      for (int d = 0; d < NDIG; ++d)
        acc[mti][d] = __builtin_amdgcn_mfma_i32_16x16x64_i8(af, bcur[d], acc[mti][d], 0, 0, 0);
    }
    #pragma unroll
    for (int d = 0; d < NDIG; ++d) bcur[d] = bnxt[d];
    #pragma unroll
    for (int mti = 0; mti < 5; ++mti) acur[mti] = anxt[mti];
  }
  // digit combine (exact integer < 2^53) -> LDS tile (row = t, col = o-in-tile)
  #pragma unroll
  for (int mti = 0; mti < 5; ++mti)
    #pragma unroll
    for (int r = 0; r < 4; ++r) {
      int m = wave * 80 + mti * 16 + quad * 4 + r;
      if (m < TT) {
        double v = (double)acc[mti][0][r]
                 + 256.0      * (double)acc[mti][1][r]
                 + 65536.0    * (double)acc[mti][2][r]
                 + 16777216.0 * (double)acc[mti][3][r];
        tile[m][lrow] = v;
      }
    }
  __syncthreads();

  // ---------- scan phase (verified truncated-IIR recurrence) ----------
  if (lane < 16) {
    int g = wave;                       // 4 segments of 75
    int T0 = g * 75, T1 = T0 + 75;
    int W = T0 - 63; if (W < 0) W = 0;
    int tB = W + 64, tM = (tB < T1) ? tB : T1;
    const double q   = exp(-0.1);
    const double q64 = exp(-6.4);
    const double cS  = (exp(1.0) / 10.0) * (1.0 / 268435456.0);
    double s1a = 0.0, s2a = 0.0, s1b = 0.0, s2b = 0.0;
    uint8_t* sb = s1 + (size_t)n * S1_NSTRIDE + (size_t)nt * S1_TILE + lane;
    for (int t = W; t < T0; ++t) {      // warm-up: A-scan only
      double xa = tile[t][lane];
      s2a = q * (s2a + s1a);
      s1a = q * s1a + xa;
    }
    for (int t = T0; t < tM; ++t) {     // outputs, no tail yet
      double xa = tile[t][lane];
      s2a = q * (s2a + s1a);
      s1a = q * s1a + xa;
      sb[(size_t)t * 16] = (cS * s2a >= 10.0) ? 1 : 0;
    }
    for (int t = tM; t < T1; ++t) {     // outputs with 64-lagged tail subtraction
      double xb = tile[t - 64][lane];
      double xa = tile[t][lane];
      s2b = q * (s2b + s1b);
      s1b = q * s1b + xb;
      s2a = q * (s2a + s1a);
      s1a = q * s1a + xa;
      double y = cS * (s2a - q64 * (s2b + 64.0 * s1b));
      sb[(size_t)t * 16] = (y >= 10.0) ? 1 : 0;
    }
  }
}

// ---- k_l2f: layer-2 i8-digit MFMA + IIR FIR + threshold -> final spikes ----
// Block = 4 waves, grid (128 n). 19 m-tiles over waves -> LDS -> 4-segment scan.
__global__ __launch_bounds__(256) void k_l2f(const uint8_t* __restrict__ s1,
                                             const v4i* __restrict__ Bf2,
                                             float* __restrict__ out) {
  __shared__ double tile2[TT][11];                   // 26400 B
  int tid = threadIdx.x;
  int wave = tid >> 6, lane = tid & 63;
  int n = blockIdx.x;
  int lrow = lane & 15, quad = lane >> 4;
  const uint8_t* s1n = s1 + (size_t)n * S1_NSTRIDE;
  for (int mt = wave; mt < 19; mt += 4) {
    int m0 = mt * 16;
    int trow = m0 + lrow; if (trow > TT - 1) trow = TT - 1;  // clamp
    v4i acc[NDIG];
    #pragma unroll
    for (int d = 0; d < NDIG; ++d) { acc[d][0]=0; acc[d][1]=0; acc[d][2]=0; acc[d][3]=0; }
    for (int ks = 0; ks < NKS2; ++ks) {
      // A-frag: 16 h-bytes = tile (ks*4+quad), t-row trow (nt-major layout)
      v4i af = *(const v4i*)(s1n + (size_t)(ks * 4 + quad) * S1_TILE + (size_t)trow * 16);
      #pragma unroll
      for (int d = 0; d < NDIG; ++d) {
        v4i bf = Bf2[(size_t)(d * NKS2 + ks) * 64 + lane];
        acc[d] = __builtin_amdgcn_mfma_i32_16x16x64_i8(af, bf, acc[d], 0, 0, 0);
      }
    }
    #pragma unroll
    for (int r = 0; r < 4; ++r) {
      int m = m0 + quad * 4 + r;
      if (m < TT && lrow < N_O) {
        double v = (double)acc[0][r]
                 + 256.0      * (double)acc[1][r]
                 + 65536.0    * (double)acc[2][r]
                 + 16777216.0 * (double)acc[3][r];
        tile2[m][lrow] = v;
      }
    }
  }
  __syncthreads();
  if (lane < N_O) {
    int g = wave;
    int T0 = g * 75, T1 = T0 + 75;
    int W = T0 - 63; if (W < 0) W = 0;
    int tB = W + 64, tM = (tB < T1) ? tB : T1;
    const double q   = exp(-0.1);
    const double q64 = exp(-6.4);
    const double cS  = (exp(1.0) / 10.0) * (1.0 / 268435456.0);
    double s1a = 0.0, s2a = 0.0, s1b = 0.0, s2b = 0.0;
    float* ob = out + (size_t)n * N_O * TT + (size_t)lane * TT;
    for (int t = W; t < T0; ++t) {
      double xa = tile2[t][lane];
      s2a = q * (s2a + s1a);
      s1a = q * s1a + xa;
    }
    for (int t = T0; t < tM; ++t) {
      double xa = tile2[t][lane];
      s2a = q * (s2a + s1a);
      s1a = q * s1a + xa;
      ob[t] = (cS * s2a >= 10.0) ? 1.0f : 0.0f;
    }
    for (int t = tM; t < T1; ++t) {
      double xb = tile2[t - 64][lane];
      double xa = tile2[t][lane];
      s2b = q * (s2b + s1b);
      s1b = q * s1b + xb;
      s2a = q * (s2a + s1a);
      s1a = q * s1a + xa;
      double y = cS * (s2a - q64 * (s2b + 64.0 * s1b));
      ob[t] = (y >= 10.0) ? 1.0f : 0.0f;
    }
  }
}

extern "C" void kernel_launch(void* const* d_in, const int* in_sizes, int n_in,
                              void* d_out, int out_size, void* d_ws, size_t ws_size,
                              hipStream_t stream) {
  const float* img   = (const float*)d_in[0];
  const float* randu = (const float*)d_in[1];
  const float* W1    = (const float*)d_in[2];
  const float* W2    = (const float*)d_in[3];
  float* out = (float*)d_out;

  char* ws = (char*)d_ws;
  size_t off = 0;
  auto alloc = [&](size_t bytes) -> void* {
    void* p = ws + off;
    off = (off + bytes + 511) & ~(size_t)511;
    return p;
  };
  uint32_t* s0w = (uint32_t*)alloc((size_t)N_B * TT * NW * sizeof(uint32_t));   // 4.0 MB
  v4i*      Bf  = (v4i*)     alloc((size_t)NDIG * NTILES * NKS * 64 * 16);      // 1.4 MB
  v4i*      Bf2 = (v4i*)     alloc((size_t)NDIG * NKS2 * 64 * 16);              // 28 KB
  uint8_t*  s1  = (uint8_t*) alloc((size_t)N_B * S1_NSTRIDE);                   // 17.2 MB
  if (off > ws_size) return;

  k_pack    <<<dim3(5, N_B), 64, 0, stream>>>(randu, img, s0w);
  k_bprepall<<<dim3(NDIG * NTILES * NKS + NDIG * NKS2), 64, 0, stream>>>(W1, W2, Bf, Bf2);
  k_fused2  <<<dim3(NTILES, N_B), 256, 0, stream>>>(s0w, Bf, s1);
  k_l2f     <<<dim3(N_B), 256, 0, stream>>>(s1, Bf2, out);
}